// Round 5
// baseline (129.920 us; speedup 1.0000x reference)
//
#include <hip/hip_runtime.h>

#define IMG   4096
#define TW    64             // tile width
#define TH    32             // tile height (per tile)
#define NT    4              // tiles per block (vertical)
#define GR    36             // gray rows  (TH + 4)
#define GC    68             // gray cols  (TW + 4)
#define GN    (GR * GC)      // 2448 floats = 9792 B per buffer
#define NBX   (IMG / TW)     // 64
#define NBYT  (IMG / TH)     // 128 tile-rows
#define W103  3.33333333333333f   // 10/3 (x3 scharr scale deferred to epilogue)

typedef float f32x4 __attribute__((ext_vector_type(4)));

__global__ __launch_bounds__(256, 4)
void harris_fused(const float* __restrict__ x,
                  float* __restrict__ out_edge,
                  float* __restrict__ out_eig)
{
    __shared__ float s_gray[2][GN];          // 19,584 B total -> up to 8 blocks/CU by LDS

    const int tid = threadIdx.x;
    const int bx = blockIdx.x, byy = blockIdx.y;
    const int gx0 = bx * TW - 2;
    const bool bxi = (bx > 0) && (bx < NBX - 1);

    const float* __restrict__ x0 = x;
    const float* __restrict__ x1 = x + (size_t)IMG * IMG;
    const float* __restrict__ x2 = x + 2 * (size_t)IMG * IMG;

    // per-thread linear offsets within a tile (constant across tiles)
    int lin[10];
    #pragma unroll
    for (int k = 0; k < 10; ++k) {
        int idx = tid + k * 256;
        int r = (int)((unsigned)idx / (unsigned)GC);
        int c = idx - r * GC;
        lin[k] = r * IMG + c;
    }

    float r0[10], r1[10], r2[10];            // staged raw channels for NEXT tile

    // ---- issue: fire the 30 global loads for tile `ty` into registers ----
    auto issue = [&](int ty) {
        const int gy0n = ty * TH - 2;
        const int base = gy0n * IMG + gx0;
        const bool tin = bxi && (ty > 0) && (ty < NBYT - 1);
        if (tin) {
            #pragma unroll
            for (int k = 0; k < 9; ++k) {
                int off = base + lin[k];
                r0[k] = x0[off]; r1[k] = x1[off]; r2[k] = x2[off];
            }
            if (tid < GN - 9 * 256) {        // tail: 144 active threads
                int off = base + lin[9];
                r0[9] = x0[off]; r1[9] = x1[off]; r2[9] = x2[off];
            } else { r0[9] = 0.f; r1[9] = 0.f; r2[9] = 0.f; }
        } else {
            #pragma unroll
            for (int k = 0; k < 10; ++k) {
                int idx = tid + k * 256;
                float a = 0.f, b = 0.f, c2 = 0.f;
                if (idx < GN) {
                    int r = (int)((unsigned)idx / (unsigned)GC);
                    int c = idx - r * GC;
                    int gy = gy0n + r, gx = gx0 + c;
                    if ((unsigned)gy < (unsigned)IMG && (unsigned)gx < (unsigned)IMG) {
                        int off = gy * IMG + gx;
                        a = x0[off]; b = x1[off]; c2 = x2[off];
                    }
                }
                r0[k] = a; r1[k] = b; r2[k] = c2;
            }
        }
    };

    // ---- commit: gray-FMA the staged registers and write them to LDS ----
    auto commit = [&](float* buf) {
        #pragma unroll
        for (int k = 0; k < 9; ++k) {
            int idx = tid + k * 256;
            buf[idx] = 0.299f * r0[k] + 0.587f * r1[k] + 0.114f * r2[k];
        }
        {   int idx = tid + 9 * 256;
            if (idx < GN)
                buf[idx] = 0.299f * r0[9] + 0.587f * r1[9] + 0.114f * r2[9];
        }
    };

    const int tx = tid & 7;          // 0..7  -> col group
    const int v  = tid >> 3;         // 0..31 -> output row within tile
    const int c0 = tx * 8;           // gray-local col base (16B aligned)
    const int W0b = bx * TW;

    // ---- compute: separable Scharr + 3x3 box + epilogues for one tile ----
    auto compute = [&](const float* buf, int ty) {
        const int H0 = ty * TH;
        float ga[12], gb[12], gcx[12];
        float axx[10], ayy[10], axy[10];
        #pragma unroll
        for (int e = 0; e < 10; ++e) { axx[e] = 0.f; ayy[e] = 0.f; axy[e] = 0.f; }

        auto loadrow = [&](float* dst, int l) {
            const float4* p = reinterpret_cast<const float4*>(&buf[(v + l) * GC + c0]);
            float4 t0 = p[0], t1 = p[1], t2 = p[2];
            dst[0] = t0.x; dst[1] = t0.y; dst[2]  = t0.z; dst[3]  = t0.w;
            dst[4] = t1.x; dst[5] = t1.y; dst[6]  = t1.z; dst[7]  = t1.w;
            dst[8] = t2.x; dst[9] = t2.y; dst[10] = t2.z; dst[11] = t2.w;
        };

        auto contrib = [&](const float* top, const float* mid, const float* bot, int K) {
            float s[12], d[12];
            #pragma unroll
            for (int j = 0; j < 12; ++j) {
                s[j] = (top[j] + bot[j]) + W103 * mid[j];   // vertical smooth (/3)
                d[j] = bot[j] - top[j];                      // vertical diff
            }
            float ix[10], iy[10];
            #pragma unroll
            for (int e = 0; e < 10; ++e) {
                ix[e] = s[e + 2] - s[e];                               // Ix/3
                iy[e] = (d[e] + d[e + 2]) + W103 * d[e + 1];           // Iy/3
            }
            if (bx == 0       && tx == 0) { ix[0] = 0.f; iy[0] = 0.f; }
            if (bx == NBX - 1 && tx == 7) { ix[9] = 0.f; iy[9] = 0.f; }
            bool row_ok = true;
            if (K == 0 && ty == 0        && v == 0)      row_ok = false;  // edge row -1
            if (K == 2 && ty == NBYT - 1 && v == TH - 1) row_ok = false;  // edge row 4096
            if (row_ok) {
                #pragma unroll
                for (int e = 0; e < 10; ++e) {
                    axx[e] += ix[e] * ix[e];
                    ayy[e] += iy[e] * iy[e];
                    axy[e] += ix[e] * iy[e];
                }
            }
            if (K == 1) {    // center row: edge magnitude = 1.5*(|ix'|+|iy'|)
                f32x4 m0, m1;
                m0.x = 1.5f * (fabsf(ix[1]) + fabsf(iy[1]));
                m0.y = 1.5f * (fabsf(ix[2]) + fabsf(iy[2]));
                m0.z = 1.5f * (fabsf(ix[3]) + fabsf(iy[3]));
                m0.w = 1.5f * (fabsf(ix[4]) + fabsf(iy[4]));
                m1.x = 1.5f * (fabsf(ix[5]) + fabsf(iy[5]));
                m1.y = 1.5f * (fabsf(ix[6]) + fabsf(iy[6]));
                m1.z = 1.5f * (fabsf(ix[7]) + fabsf(iy[7]));
                m1.w = 1.5f * (fabsf(ix[8]) + fabsf(iy[8]));
                const int off = (H0 + v) * IMG + W0b + c0;
                __builtin_nontemporal_store(m0, reinterpret_cast<f32x4*>(&out_edge[off]));
                __builtin_nontemporal_store(m1, reinterpret_cast<f32x4*>(&out_edge[off + 4]));
            }
        };

        loadrow(ga, 0); loadrow(gb, 1); loadrow(gcx, 2);
        contrib(ga, gb, gcx, 0);
        loadrow(ga, 3);
        contrib(gb, gcx, ga, 1);
        loadrow(gb, 4);
        contrib(gcx, ga, gb, 2);

        f32x4 e0, e1;
        #pragma unroll
        for (int q = 0; q < 8; ++q) {
            float sxx = axx[q] + axx[q + 1] + axx[q + 2];
            float syy = ayy[q] + ayy[q + 1] + ayy[q + 2];
            float sxy = axy[q] + axy[q + 1] + axy[q + 2];
            float diff = sxx - syy;
            float tr   = sxx + syy;
            float val  = 9.0f * (tr - sqrtf(diff * diff + 4.0f * sxy * sxy));
            if (q < 4) e0[q] = val; else e1[q - 4] = val;
        }
        const int off = (H0 + v) * IMG + W0b + c0;
        __builtin_nontemporal_store(e0, reinterpret_cast<f32x4*>(&out_eig[off]));
        __builtin_nontemporal_store(e1, reinterpret_cast<f32x4*>(&out_eig[off + 4]));
    };

    // ---- pipelined tile loop: load(t+1) under compute(t), one barrier per tile ----
    int cur = 0;
    issue(byy * NT);
    commit(s_gray[0]);
    __syncthreads();

    for (int t = 0; t < NT; ++t) {
        const int ty = byy * NT + t;
        if (t + 1 < NT) issue(ty + 1);                 // loads in flight during compute
        compute(s_gray[cur], ty);
        if (t + 1 < NT) {
            commit(s_gray[cur ^ 1]);                   // vmcnt waits land here, after compute
            __syncthreads();
            cur ^= 1;
        }
    }
}

extern "C" void kernel_launch(void* const* d_in, const int* in_sizes, int n_in,
                              void* d_out, int out_size, void* d_ws, size_t ws_size,
                              hipStream_t stream) {
    const float* x = (const float*)d_in[0];
    float* out      = (float*)d_out;
    float* out_edge = out;                       // output 0: (1,4096,4096)
    float* out_eig  = out + (size_t)IMG * IMG;   // output 1: (1,4096,4096)

    dim3 grid(NBX, NBYT / NT);
    harris_fused<<<grid, dim3(256), 0, stream>>>(x, out_edge, out_eig);
}